// Round 13
// baseline (143.077 us; speedup 1.0000x reference)
//
#include <hip/hip_runtime.h>

#define TT 512   // timesteps
#define ID 32    // input features
#define HD 64    // hidden
#define NTK 8    // tickers
#define RPB 4    // batch rows per block
#define ZPAD 80  // f16 elems per zbuf row (measured conflict-free)

typedef __attribute__((ext_vector_type(8))) _Float16 half8;
typedef __attribute__((ext_vector_type(2))) __fp16 fp16x2;
typedef __attribute__((ext_vector_type(4))) float f32x4;

#define L2E 1.44269504089f

__device__ __forceinline__ f32x4 MF(half8 a, half8 b, f32x4 c) {
    return __builtin_amdgcn_mfma_f32_16x16x32_f16(a, b, c, 0, 0, 0);
}

// two float4 -> half8 via 4x v_cvt_pkrtz_f16_f32
__device__ __forceinline__ half8 cvt8(float4 a, float4 b) {
    union { fp16x2 h2[4]; half8 h8; } u;
    u.h2[0] = __builtin_amdgcn_cvt_pkrtz(a.x, a.y);
    u.h2[1] = __builtin_amdgcn_cvt_pkrtz(a.z, a.w);
    u.h2[2] = __builtin_amdgcn_cvt_pkrtz(b.x, b.y);
    u.h2[3] = __builtin_amdgcn_cvt_pkrtz(b.z, b.w);
    return u.h8;
}

// 128 blocks x 256 threads (4 waves = 1/SIMD), 4 batch rows per block.
// Group-of-4 xproj amortization (R11/R12 skeleton) with x read DIRECTLY as
// f32 (no cvt_x pre-pass, no workspace): group loads are clamped
// UNCONDITIONAL 2x float4 issued in a group's STEP(0) build slot, converted
// by pkrtz 3 barriers (~1700cy) later, used one step after that — slack far
// exceeds HBM latency, so the loads stay hoisted (R10's failure was guarded
// per-step loads that the scheduler sank).
__global__ __launch_bounds__(256, 1) void lstm8(
    const float* __restrict__ x,       // (B, T, I)
    const float* __restrict__ w_ih,    // (4H, I)
    const float* __restrict__ w_hh,    // (4H, H)
    const float* __restrict__ b_ih,    // (4H)
    const float* __restrict__ b_hh,    // (4H)
    const float* __restrict__ w_fc,    // (NTK, H)
    const float* __restrict__ b_fc,    // (NTK)
    float* __restrict__ out)           // (B, NTK)
{
    const int tid = threadIdx.x;
    const int wv  = tid >> 6;          // wave 0..3
    const int l   = tid & 63;
    const int l15 = l & 15;
    const int lq  = l >> 4;            // k-chunk; = batch row this lane activates
    const int abr = l15 >> 2;          // batch row this lane's A-row supplies
    const int sst = l15 & 3;           // time slot this lane's A-row supplies
    const int r0  = blockIdx.x * RPB;

    __shared__ __align__(16) _Float16 zbuf[2][RPB][ZPAD];   // double-buffered h

    // ---- loop-invariant B fragments (W^T) + bias C-in ----
    // B layout: col n = lane&15, k = (lane>>4)*8 + j. nt = gate type (i,f,g,o).
    half8 Bh0[4], Bh1[4], Bx[4];
    f32x4 biasC[4];
    #pragma unroll
    for (int nt = 0; nt < 4; ++nt) {
        const int n = nt * 64 + wv * 16 + l15;
        const float bias = b_ih[n] + b_hh[n];
        biasC[nt] = (f32x4){bias, bias, bias, bias};
        const float* ph = w_hh + n * HD + lq * 8;
        float4 p0 = ((const float4*)ph)[0], p1 = ((const float4*)ph)[1];
        Bh0[nt] = (half8){(_Float16)p0.x, (_Float16)p0.y, (_Float16)p0.z, (_Float16)p0.w,
                          (_Float16)p1.x, (_Float16)p1.y, (_Float16)p1.z, (_Float16)p1.w};
        p0 = ((const float4*)(ph + 32))[0]; p1 = ((const float4*)(ph + 32))[1];
        Bh1[nt] = (half8){(_Float16)p0.x, (_Float16)p0.y, (_Float16)p0.z, (_Float16)p0.w,
                          (_Float16)p1.x, (_Float16)p1.y, (_Float16)p1.z, (_Float16)p1.w};
        const float* px = w_ih + n * ID + lq * 8;
        p0 = ((const float4*)px)[0]; p1 = ((const float4*)px)[1];
        Bx[nt]  = (half8){(_Float16)p0.x, (_Float16)p0.y, (_Float16)p0.z, (_Float16)p0.w,
                          (_Float16)p1.x, (_Float16)p1.y, (_Float16)p1.z, (_Float16)p1.w};
    }

    zbuf[0][tid >> 6][tid & 63] = (_Float16)0.0f;   // h(0) = 0

    // x: lane loads x[r0+abr][t+sst][lq*8 .. +8) once per 4-step group (f32)
    const float* xbase = x + ((size_t)(r0 + abr) * TT + sst) * ID + lq * 8;

    float4 xaf0, xaf1, xbf0, xbf1;
    // prologue: xpA for group t=0; xn0h = x(t=4) half8 feeds group B's build
    xaf0 = ((const float4*)xbase)[0]; xaf1 = ((const float4*)xbase)[1];
    half8 xc = cvt8(xaf0, xaf1);
    f32x4 xpA_O = MF(xc, Bx[3], biasC[3]);
    f32x4 xpA_F = MF(xc, Bx[1], biasC[1]);
    f32x4 xpA_I = MF(xc, Bx[0], biasC[0]);
    f32x4 xpA_G = MF(xc, Bx[2], biasC[2]);
    xbf0 = ((const float4*)(xbase + 4 * ID))[0];
    xbf1 = ((const float4*)(xbase + 4 * ID))[1];
    half8 xn0h = cvt8(xbf0, xbf1);
    half8 xn1h;
    f32x4 xpB_O, xpB_F, xpB_I, xpB_G;
    float c_ = 0.0f;
    __syncthreads();

    // One step: z ds_reads -> build-slot work (group x load / x-MFMA / cvt,
    // all z-independent, covers z latency) -> 8 h-MFMAs (streams O,F,I,G) ->
    // early eo/ef/ei -> short eg->c->h tail -> h write.
#define STEP(S, RB, WB, XPO, XPF, XPI, XPG, XBUILD)                                 \
    {                                                                               \
        half8 z0 = *(const half8*)&zbuf[RB][abr][lq * 8];                           \
        half8 z1 = *(const half8*)&zbuf[RB][abr][32 + lq * 8];                      \
        XBUILD;                                                                     \
        f32x4 aO = MF(z0, Bh0[3], XPO);                                             \
        f32x4 aF = MF(z0, Bh0[1], XPF);                                             \
        f32x4 aI = MF(z0, Bh0[0], XPI);                                             \
        f32x4 aG = MF(z0, Bh0[2], XPG);                                             \
        aO = MF(z1, Bh1[3], aO);                                                    \
        aF = MF(z1, Bh1[1], aF);                                                    \
        aI = MF(z1, Bh1[0], aI);                                                    \
        aG = MF(z1, Bh1[2], aG);                                                    \
        const float eo = __builtin_amdgcn_exp2f(-L2E * aO[S]);                      \
        const float ef = __builtin_amdgcn_exp2f(-L2E * aF[S]);                      \
        const float ei = __builtin_amdgcn_exp2f(-L2E * aI[S]);                      \
        const float to = 1.0f + eo;                                                 \
        const float rf = __builtin_amdgcn_rcpf(1.0f + ef);                          \
        const float ti = 1.0f + ei;                                                 \
        const float eg = __builtin_amdgcn_exp2f(fminf(2.0f * L2E * aG[S], 60.0f));  \
        const float rig = __builtin_amdgcn_rcpf(fmaf(eg, ti, ti));                  \
        c_ = fmaf(c_, rf, fmaf(eg, rig, -rig));                                     \
        const float ec = __builtin_amdgcn_exp2f(fminf(2.0f * L2E * c_, 60.0f));     \
        const float rh = __builtin_amdgcn_rcpf(fmaf(ec, to, to));                   \
        const float hh = fmaf(ec, rh, -rh);                                         \
        zbuf[WB][lq][wv * 16 + l15] = (_Float16)hh;                                 \
    }

    for (int t = 0; t < TT; t += 8) {
        const int tA = (t + 8  < TT) ? t + 8  : t;   // x for next iter's group A
        const int tB = (t + 12 < TT) ? t + 12 : t;   // x for next iter's group B
        // group A (t..t+3): uses xpA; builds xpB from xn0h = x(t+4);
        // loads x(tA) raw, converts it in step 3's build slot.
        STEP(0, 0, 1, xpA_O, xpA_F, xpA_I, xpA_G,
             { const float* s_ = xbase + (size_t)tA * ID;
               xaf0 = ((const float4*)s_)[0]; xaf1 = ((const float4*)s_)[1];
               xpB_O = MF(xn0h, Bx[3], biasC[3]); });
        __syncthreads();
        STEP(1, 1, 0, xpA_O, xpA_F, xpA_I, xpA_G,
             { xpB_F = MF(xn0h, Bx[1], biasC[1]); });
        __syncthreads();
        STEP(2, 0, 1, xpA_O, xpA_F, xpA_I, xpA_G,
             { xpB_I = MF(xn0h, Bx[0], biasC[0]); });
        __syncthreads();
        STEP(3, 1, 0, xpA_O, xpA_F, xpA_I, xpA_G,
             { xpB_G = MF(xn0h, Bx[2], biasC[2]);
               xn1h = cvt8(xaf0, xaf1); });
        __syncthreads();
        // group B (t+4..t+7): uses xpB; builds xpA from xn1h = x(t+8);
        // loads x(tB) raw, converts in step 3's build slot.
        STEP(0, 0, 1, xpB_O, xpB_F, xpB_I, xpB_G,
             { const float* s_ = xbase + (size_t)tB * ID;
               xbf0 = ((const float4*)s_)[0]; xbf1 = ((const float4*)s_)[1];
               xpA_O = MF(xn1h, Bx[3], biasC[3]); });
        __syncthreads();
        STEP(1, 1, 0, xpB_O, xpB_F, xpB_I, xpB_G,
             { xpA_F = MF(xn1h, Bx[1], biasC[1]); });
        __syncthreads();
        STEP(2, 0, 1, xpB_O, xpB_F, xpB_I, xpB_G,
             { xpA_I = MF(xn1h, Bx[0], biasC[0]); });
        __syncthreads();
        STEP(3, 1, 0, xpB_O, xpB_F, xpB_I, xpB_G,
             { xpA_G = MF(xn1h, Bx[2], biasC[2]);
               xn0h = cvt8(xbf0, xbf1); });
        __syncthreads();
    }
#undef STEP

    // h(T) in zbuf[0] (last step writes buf 0). FC head: one (row,ticker)/thread.
    if (tid < RPB * NTK) {
        const int rr = tid >> 3;
        const int tk = tid & 7;
        float a = b_fc[tk];
        const float* wf = w_fc + tk * HD;
        #pragma unroll
        for (int j = 0; j < HD; ++j)
            a = fmaf((float)zbuf[0][rr][j], wf[j], a);
        out[(r0 + rr) * NTK + tk] = a;
    }
}

extern "C" void kernel_launch(void* const* d_in, const int* in_sizes, int n_in,
                              void* d_out, int out_size, void* d_ws, size_t ws_size,
                              hipStream_t stream) {
    const float* x    = (const float*)d_in[0];
    const float* w_ih = (const float*)d_in[1];
    const float* w_hh = (const float*)d_in[2];
    const float* b_ih = (const float*)d_in[3];
    const float* b_hh = (const float*)d_in[4];
    const float* w_fc = (const float*)d_in[5];
    const float* b_fc = (const float*)d_in[6];
    float* out = (float*)d_out;

    const int nx = in_sizes[0];              // B*T*I
    const int B  = nx / (TT * ID);           // 512

    lstm8<<<dim3(B / RPB), dim3(256), 0, stream>>>(x, w_ih, w_hh, b_ih, b_hh,
                                                   w_fc, b_fc, out);
}

// Round 14
// 119.040 us; speedup vs baseline: 1.2019x; 1.2019x over previous
//
#include <hip/hip_runtime.h>

#define TT 512    // timesteps
#define ID 32     // input features
#define HD 64     // hidden
#define NTK 8     // tickers
#define RPB 4     // batch rows per block
#define ZPAD 80   // f16 elems per zbuf row (measured conflict-free)
// x LDS row pitch: 2048 16B-chunks + 8 skew chunks -> 64-lane group reads are
// exactly 2-way bank-aliased (free). In f16 units:
#define XPITCH_H 16448                    // (2048+8)*8
#define XBYTES   (RPB * XPITCH_H * 2)     // 131584
#define ZBYTES   (2 * RPB * ZPAD * 2)     // 1280
#define SHBYTES  (XBYTES + ZBYTES)

typedef __attribute__((ext_vector_type(8))) _Float16 half8;
typedef __attribute__((ext_vector_type(2))) __fp16 fp16x2;
typedef __attribute__((ext_vector_type(4))) float f32x4;

#define L2E 1.44269504089f

__device__ __forceinline__ f32x4 MF(half8 a, half8 b, f32x4 c) {
    return __builtin_amdgcn_mfma_f32_16x16x32_f16(a, b, c, 0, 0, 0);
}

// two float4 -> half8 via 4x v_cvt_pkrtz_f16_f32
__device__ __forceinline__ half8 cvt8(float4 a, float4 b) {
    union { fp16x2 h2[4]; half8 h8; } u;
    u.h2[0] = __builtin_amdgcn_cvt_pkrtz(a.x, a.y);
    u.h2[1] = __builtin_amdgcn_cvt_pkrtz(a.z, a.w);
    u.h2[2] = __builtin_amdgcn_cvt_pkrtz(b.x, b.y);
    u.h2[3] = __builtin_amdgcn_cvt_pkrtz(b.z, b.w);
    return u.h8;
}

// 128 blocks x 256 threads (4 waves = 1/SIMD), 4 batch rows per block.
// The block's ENTIRE x slice (4 x 512 x 32 f16 = 128KB) is staged into LDS
// once at kernel start (bulk coalesced f32 reads + pkrtz), so the recurrent
// loop has ZERO global traffic: __syncthreads' implicit vmcnt(0) drain
// (which exposed global-load latency every step in R13, +200cy/step) is
// free. Group-of-4 xproj amortization + spread x-MFMAs + O/F/I/G act
// streams as R12.
__global__ __launch_bounds__(256, 1) void lstm9(
    const float* __restrict__ x,       // (B, T, I)
    const float* __restrict__ w_ih,    // (4H, I)
    const float* __restrict__ w_hh,    // (4H, H)
    const float* __restrict__ b_ih,    // (4H)
    const float* __restrict__ b_hh,    // (4H)
    const float* __restrict__ w_fc,    // (NTK, H)
    const float* __restrict__ b_fc,    // (NTK)
    float* __restrict__ out)           // (B, NTK)
{
    extern __shared__ __align__(16) char smem[];
    _Float16* xlds = (_Float16*)smem;                              // [RPB][XPITCH_H]
    _Float16 (*zbuf)[RPB][ZPAD] = (_Float16 (*)[RPB][ZPAD])(smem + XBYTES);

    const int tid = threadIdx.x;
    const int wv  = tid >> 6;          // wave 0..3
    const int l   = tid & 63;
    const int l15 = l & 15;
    const int lq  = l >> 4;            // k-chunk; = batch row this lane activates
    const int abr = l15 >> 2;          // batch row this lane's A-row supplies
    const int sst = l15 & 3;           // time slot this lane's A-row supplies
    const int r0  = blockIdx.x * RPB;

    // ---- loop-invariant B fragments (W^T) + bias C-in ----
    // B layout: col n = lane&15, k = (lane>>4)*8 + j. nt = gate type (i,f,g,o).
    half8 Bh0[4], Bh1[4], Bx[4];
    f32x4 biasC[4];
    #pragma unroll
    for (int nt = 0; nt < 4; ++nt) {
        const int n = nt * 64 + wv * 16 + l15;
        const float bias = b_ih[n] + b_hh[n];
        biasC[nt] = (f32x4){bias, bias, bias, bias};
        const float* ph = w_hh + n * HD + lq * 8;
        float4 p0 = ((const float4*)ph)[0], p1 = ((const float4*)ph)[1];
        Bh0[nt] = (half8){(_Float16)p0.x, (_Float16)p0.y, (_Float16)p0.z, (_Float16)p0.w,
                          (_Float16)p1.x, (_Float16)p1.y, (_Float16)p1.z, (_Float16)p1.w};
        p0 = ((const float4*)(ph + 32))[0]; p1 = ((const float4*)(ph + 32))[1];
        Bh1[nt] = (half8){(_Float16)p0.x, (_Float16)p0.y, (_Float16)p0.z, (_Float16)p0.w,
                          (_Float16)p1.x, (_Float16)p1.y, (_Float16)p1.z, (_Float16)p1.w};
        const float* px = w_ih + n * ID + lq * 8;
        p0 = ((const float4*)px)[0]; p1 = ((const float4*)px)[1];
        Bx[nt]  = (half8){(_Float16)p0.x, (_Float16)p0.y, (_Float16)p0.z, (_Float16)p0.w,
                          (_Float16)p1.x, (_Float16)p1.y, (_Float16)p1.z, (_Float16)p1.w};
    }

    // ---- stage x slice into LDS: 4 rows x 2048 chunks (16B), 8 chunks/thread/row ----
    #pragma unroll
    for (int r = 0; r < RPB; ++r) {
        const float4* src = (const float4*)(x + ((size_t)(r0 + r) * TT) * ID);
        _Float16* dst = xlds + r * XPITCH_H;
        #pragma unroll
        for (int k = 0; k < 8; ++k) {
            const int c = tid + k * 256;            // chunk 0..2047
            float4 a = src[2 * c];
            float4 b = src[2 * c + 1];
            *(half8*)(dst + c * 8) = cvt8(a, b);    // linear: conflict-free
        }
    }
    zbuf[0][tid >> 6][tid & 63] = (_Float16)0.0f;   // h(0) = 0
    __syncthreads();

    // lane's x chunk for step t: xlds[abr][((t+sst)*4 + lq)*8 ..+8)
    const _Float16* xlane = xlds + abr * XPITCH_H + (sst * 4 + lq) * 8;
    auto ldsx = [&](int t) -> half8 {
        return *(const half8*)(xlane + t * (4 * 8));
    };

    // prologue: xpA for group t=0; xn0 = x(t=4) feeds group B's build
    half8 xc = ldsx(0);
    f32x4 xpA_O = MF(xc, Bx[3], biasC[3]);
    f32x4 xpA_F = MF(xc, Bx[1], biasC[1]);
    f32x4 xpA_I = MF(xc, Bx[0], biasC[0]);
    f32x4 xpA_G = MF(xc, Bx[2], biasC[2]);
    half8 xn0 = ldsx(4);
    half8 xn1;
    f32x4 xpB_O, xpB_F, xpB_I, xpB_G;
    float c_ = 0.0f;

    // One step: z ds_reads -> build slot (next-group x ds_read / x-MFMA,
    // z-independent, covers z latency) -> 8 h-MFMAs (streams O,F,I,G) ->
    // early eo/ef/ei -> short eg->c->h tail -> h write. 1 barrier/step.
#define STEP(S, RB, WB, XPO, XPF, XPI, XPG, XBUILD)                                 \
    {                                                                               \
        half8 z0 = *(const half8*)&zbuf[RB][abr][lq * 8];                           \
        half8 z1 = *(const half8*)&zbuf[RB][abr][32 + lq * 8];                      \
        XBUILD;                                                                     \
        f32x4 aO = MF(z0, Bh0[3], XPO);                                             \
        f32x4 aF = MF(z0, Bh0[1], XPF);                                             \
        f32x4 aI = MF(z0, Bh0[0], XPI);                                             \
        f32x4 aG = MF(z0, Bh0[2], XPG);                                             \
        aO = MF(z1, Bh1[3], aO);                                                    \
        aF = MF(z1, Bh1[1], aF);                                                    \
        aI = MF(z1, Bh1[0], aI);                                                    \
        aG = MF(z1, Bh1[2], aG);                                                    \
        const float eo = __builtin_amdgcn_exp2f(-L2E * aO[S]);                      \
        const float ef = __builtin_amdgcn_exp2f(-L2E * aF[S]);                      \
        const float ei = __builtin_amdgcn_exp2f(-L2E * aI[S]);                      \
        const float to = 1.0f + eo;                                                 \
        const float rf = __builtin_amdgcn_rcpf(1.0f + ef);                          \
        const float ti = 1.0f + ei;                                                 \
        const float eg = __builtin_amdgcn_exp2f(fminf(2.0f * L2E * aG[S], 60.0f));  \
        const float rig = __builtin_amdgcn_rcpf(fmaf(eg, ti, ti));                  \
        c_ = fmaf(c_, rf, fmaf(eg, rig, -rig));                                     \
        const float ec = __builtin_amdgcn_exp2f(fminf(2.0f * L2E * c_, 60.0f));     \
        const float rh = __builtin_amdgcn_rcpf(fmaf(ec, to, to));                   \
        const float hh = fmaf(ec, rh, -rh);                                         \
        zbuf[WB][lq][wv * 16 + l15] = (_Float16)hh;                                 \
    }

    for (int t = 0; t < TT; t += 8) {
        const int tA = (t + 8  < TT) ? t + 8  : t;   // x for next iter's group A
        const int tB = (t + 12 < TT) ? t + 12 : t;   // x for next iter's group B
        // group A (t..t+3): uses xpA, builds xpB from xn0 = x(t+4)
        STEP(0, 0, 1, xpA_O, xpA_F, xpA_I, xpA_G,
             { xn1 = ldsx(tA); xpB_O = MF(xn0, Bx[3], biasC[3]); });
        __syncthreads();
        STEP(1, 1, 0, xpA_O, xpA_F, xpA_I, xpA_G,
             { xpB_F = MF(xn0, Bx[1], biasC[1]); });
        __syncthreads();
        STEP(2, 0, 1, xpA_O, xpA_F, xpA_I, xpA_G,
             { xpB_I = MF(xn0, Bx[0], biasC[0]); });
        __syncthreads();
        STEP(3, 1, 0, xpA_O, xpA_F, xpA_I, xpA_G,
             { xpB_G = MF(xn0, Bx[2], biasC[2]); });
        __syncthreads();
        // group B (t+4..t+7): uses xpB, builds xpA from xn1 = x(t+8)
        STEP(0, 0, 1, xpB_O, xpB_F, xpB_I, xpB_G,
             { xn0 = ldsx(tB); xpA_O = MF(xn1, Bx[3], biasC[3]); });
        __syncthreads();
        STEP(1, 1, 0, xpB_O, xpB_F, xpB_I, xpB_G,
             { xpA_F = MF(xn1, Bx[1], biasC[1]); });
        __syncthreads();
        STEP(2, 0, 1, xpB_O, xpB_F, xpB_I, xpB_G,
             { xpA_I = MF(xn1, Bx[0], biasC[0]); });
        __syncthreads();
        STEP(3, 1, 0, xpB_O, xpB_F, xpB_I, xpB_G,
             { xpA_G = MF(xn1, Bx[2], biasC[2]); });
        __syncthreads();
    }
#undef STEP

    // h(T) in zbuf[0] (last step writes buf 0). FC head: one (row,ticker)/thread.
    if (tid < RPB * NTK) {
        const int rr = tid >> 3;
        const int tk = tid & 7;
        float a = b_fc[tk];
        const float* wf = w_fc + tk * HD;
        #pragma unroll
        for (int j = 0; j < HD; ++j)
            a = fmaf((float)zbuf[0][rr][j], wf[j], a);
        out[(r0 + rr) * NTK + tk] = a;
    }
}

extern "C" void kernel_launch(void* const* d_in, const int* in_sizes, int n_in,
                              void* d_out, int out_size, void* d_ws, size_t ws_size,
                              hipStream_t stream) {
    const float* x    = (const float*)d_in[0];
    const float* w_ih = (const float*)d_in[1];
    const float* w_hh = (const float*)d_in[2];
    const float* b_ih = (const float*)d_in[3];
    const float* b_hh = (const float*)d_in[4];
    const float* w_fc = (const float*)d_in[5];
    const float* b_fc = (const float*)d_in[6];
    float* out = (float*)d_out;

    const int nx = in_sizes[0];              // B*T*I
    const int B  = nx / (TT * ID);           // 512

    // opt-in to >64KB dynamic LDS (idempotent host call; capture-safe)
    static int attr_done = 0;
    (void)hipFuncSetAttribute((const void*)lstm9,
                              hipFuncAttributeMaxDynamicSharedMemorySize, SHBYTES);
    (void)attr_done;

    lstm9<<<dim3(B / RPB), dim3(256), SHBYTES, stream>>>(x, w_ih, w_hh, b_ih, b_hh,
                                                         w_fc, b_fc, out);
}

// Round 15
// 115.968 us; speedup vs baseline: 1.2338x; 1.0265x over previous
//
#include <hip/hip_runtime.h>

#define TT 512    // timesteps
#define ID 32     // input features
#define HD 64     // hidden
#define NTK 8     // tickers
#define RPB 4     // batch rows per block
#define ZPAD 80   // f16 elems per zbuf row (measured conflict-free)
// x LDS row pitch: 2048 16B-chunks + 8 skew chunks (2-way bank alias = free)
#define XPITCH_H 16448                    // (2048+8)*8
#define XBYTES   (RPB * XPITCH_H * 2)     // 131584
#define ZBYTES   (2 * RPB * ZPAD * 2)     // 1280
#define SHBYTES  (XBYTES + ZBYTES)

typedef __attribute__((ext_vector_type(8))) _Float16 half8;
typedef __attribute__((ext_vector_type(2))) __fp16 fp16x2;
typedef __attribute__((ext_vector_type(4))) float f32x4;

#define L2E 1.44269504089f

__device__ __forceinline__ f32x4 MF(half8 a, half8 b, f32x4 c) {
    return __builtin_amdgcn_mfma_f32_16x16x32_f16(a, b, c, 0, 0, 0);
}

// two float4 -> half8 via 4x v_cvt_pkrtz_f16_f32
__device__ __forceinline__ half8 cvt8(float4 a, float4 b) {
    union { fp16x2 h2[4]; half8 h8; } u;
    u.h2[0] = __builtin_amdgcn_cvt_pkrtz(a.x, a.y);
    u.h2[1] = __builtin_amdgcn_cvt_pkrtz(a.z, a.w);
    u.h2[2] = __builtin_amdgcn_cvt_pkrtz(b.x, b.y);
    u.h2[3] = __builtin_amdgcn_cvt_pkrtz(b.z, b.w);
    return u.h8;
}

// 128 blocks x 256 threads (4 waves = 1/SIMD), 4 batch rows per block.
// R14 skeleton (full x slice staged in LDS; zero global traffic in loop;
// group-of-4 xproj amortization; spread build x-MFMAs) + tail polish:
//  - weights/biases PRE-SCALED by act constants (i,f,o: -log2e; g: +2log2e)
//    so act = exp2(mfma result) directly — 4 fewer v_mul, shorter tail;
//  - G-stream-first MFMA order: aG retires ~58cy early, tail's serial chain
//    (eg->rig->c->ec->rh->hh) overlaps the F/I/O MFMA issue; eo lands last.
__global__ __launch_bounds__(256, 1) void lstm10(
    const float* __restrict__ x,       // (B, T, I)
    const float* __restrict__ w_ih,    // (4H, I)
    const float* __restrict__ w_hh,    // (4H, H)
    const float* __restrict__ b_ih,    // (4H)
    const float* __restrict__ b_hh,    // (4H)
    const float* __restrict__ w_fc,    // (NTK, H)
    const float* __restrict__ b_fc,    // (NTK)
    float* __restrict__ out)           // (B, NTK)
{
    extern __shared__ __align__(16) char smem[];
    _Float16* xlds = (_Float16*)smem;                              // [RPB][XPITCH_H]
    _Float16 (*zbuf)[RPB][ZPAD] = (_Float16 (*)[RPB][ZPAD])(smem + XBYTES);

    const int tid = threadIdx.x;
    const int wv  = tid >> 6;          // wave 0..3
    const int l   = tid & 63;
    const int l15 = l & 15;
    const int lq  = l >> 4;            // k-chunk; = batch row this lane activates
    const int abr = l15 >> 2;          // batch row this lane's A-row supplies
    const int sst = l15 & 3;           // time slot this lane's A-row supplies
    const int r0  = blockIdx.x * RPB;

    // ---- loop-invariant B fragments (W^T, PRE-SCALED) + bias C-in ----
    // B layout: col n = lane&15, k = (lane>>4)*8 + j. nt = gate type (i,f,g,o).
    // scale: i,f,o -> -L2E ; g -> +2*L2E  (act = exp2(result) directly)
    half8 Bh0[4], Bh1[4], Bx[4];
    f32x4 biasC[4];
    #pragma unroll
    for (int nt = 0; nt < 4; ++nt) {
        const float sc = (nt == 2) ? 2.0f * L2E : -L2E;
        const int n = nt * 64 + wv * 16 + l15;
        const float bias = sc * (b_ih[n] + b_hh[n]);
        biasC[nt] = (f32x4){bias, bias, bias, bias};
        const float* ph = w_hh + n * HD + lq * 8;
        float4 p0 = ((const float4*)ph)[0], p1 = ((const float4*)ph)[1];
        Bh0[nt] = (half8){(_Float16)(sc*p0.x), (_Float16)(sc*p0.y), (_Float16)(sc*p0.z), (_Float16)(sc*p0.w),
                          (_Float16)(sc*p1.x), (_Float16)(sc*p1.y), (_Float16)(sc*p1.z), (_Float16)(sc*p1.w)};
        p0 = ((const float4*)(ph + 32))[0]; p1 = ((const float4*)(ph + 32))[1];
        Bh1[nt] = (half8){(_Float16)(sc*p0.x), (_Float16)(sc*p0.y), (_Float16)(sc*p0.z), (_Float16)(sc*p0.w),
                          (_Float16)(sc*p1.x), (_Float16)(sc*p1.y), (_Float16)(sc*p1.z), (_Float16)(sc*p1.w)};
        const float* px = w_ih + n * ID + lq * 8;
        p0 = ((const float4*)px)[0]; p1 = ((const float4*)px)[1];
        Bx[nt]  = (half8){(_Float16)(sc*p0.x), (_Float16)(sc*p0.y), (_Float16)(sc*p0.z), (_Float16)(sc*p0.w),
                          (_Float16)(sc*p1.x), (_Float16)(sc*p1.y), (_Float16)(sc*p1.z), (_Float16)(sc*p1.w)};
    }

    // ---- stage x slice into LDS: 4 rows x 2048 chunks (16B), 8/thread/row ----
    #pragma unroll
    for (int r = 0; r < RPB; ++r) {
        const float4* src = (const float4*)(x + ((size_t)(r0 + r) * TT) * ID);
        _Float16* dst = xlds + r * XPITCH_H;
        #pragma unroll
        for (int k = 0; k < 8; ++k) {
            const int c = tid + k * 256;            // chunk 0..2047
            float4 a = src[2 * c];
            float4 b = src[2 * c + 1];
            *(half8*)(dst + c * 8) = cvt8(a, b);    // linear: conflict-free
        }
    }
    zbuf[0][tid >> 6][tid & 63] = (_Float16)0.0f;   // h(0) = 0
    __syncthreads();

    // lane's x chunk for step t: xlds[abr][((t+sst)*4 + lq)*8 ..+8)
    const _Float16* xlane = xlds + abr * XPITCH_H + (sst * 4 + lq) * 8;
    auto ldsx = [&](int t) -> half8 {
        return *(const half8*)(xlane + t * (4 * 8));
    };

    // prologue: xpA for group t=0; xn0 = x(t=4) feeds group B's build
    half8 xc = ldsx(0);
    f32x4 xpA_G = MF(xc, Bx[2], biasC[2]);
    f32x4 xpA_F = MF(xc, Bx[1], biasC[1]);
    f32x4 xpA_I = MF(xc, Bx[0], biasC[0]);
    f32x4 xpA_O = MF(xc, Bx[3], biasC[3]);
    half8 xn0 = ldsx(4);
    half8 xn1;
    f32x4 xpB_G, xpB_F, xpB_I, xpB_O;
    float c_ = 0.0f;

    // One step: z ds_reads -> build slot (z-independent) -> 8 h-MFMAs
    // (G first, O last) -> act: eg chain starts during F/I/O issue ->
    // h write. 1 barrier/step.
#define STEP(S, RB, WB, XPG, XPF, XPI, XPO, XBUILD)                                 \
    {                                                                               \
        half8 z0 = *(const half8*)&zbuf[RB][abr][lq * 8];                           \
        half8 z1 = *(const half8*)&zbuf[RB][abr][32 + lq * 8];                      \
        XBUILD;                                                                     \
        f32x4 aG = MF(z0, Bh0[2], XPG);                                             \
        f32x4 aF = MF(z0, Bh0[1], XPF);                                             \
        f32x4 aI = MF(z0, Bh0[0], XPI);                                             \
        f32x4 aO = MF(z0, Bh0[3], XPO);                                             \
        aG = MF(z1, Bh1[2], aG);                                                    \
        aF = MF(z1, Bh1[1], aF);                                                    \
        aI = MF(z1, Bh1[0], aI);                                                    \
        aO = MF(z1, Bh1[3], aO);                                                    \
        const float eg = __builtin_amdgcn_exp2f(fminf(aG[S], 60.0f));               \
        const float ef = __builtin_amdgcn_exp2f(aF[S]);                             \
        const float ei = __builtin_amdgcn_exp2f(aI[S]);                             \
        const float eo = __builtin_amdgcn_exp2f(aO[S]);                             \
        const float ti = 1.0f + ei;                                                 \
        const float rf = __builtin_amdgcn_rcpf(1.0f + ef);                          \
        const float rig = __builtin_amdgcn_rcpf(fmaf(eg, ti, ti));                  \
        c_ = fmaf(c_, rf, fmaf(eg, rig, -rig));                                     \
        const float ec = __builtin_amdgcn_exp2f(fminf(2.0f * L2E * c_, 60.0f));     \
        const float to = 1.0f + eo;                                                 \
        const float rh = __builtin_amdgcn_rcpf(fmaf(ec, to, to));                   \
        const float hh = fmaf(ec, rh, -rh);                                         \
        zbuf[WB][lq][wv * 16 + l15] = (_Float16)hh;                                 \
    }

    for (int t = 0; t < TT; t += 8) {
        const int tA = (t + 8  < TT) ? t + 8  : t;   // x for next iter's group A
        const int tB = (t + 12 < TT) ? t + 12 : t;   // x for next iter's group B
        // group A (t..t+3): uses xpA, builds xpB from xn0 = x(t+4)
        STEP(0, 0, 1, xpA_G, xpA_F, xpA_I, xpA_O,
             { xn1 = ldsx(tA); xpB_G = MF(xn0, Bx[2], biasC[2]); });
        __syncthreads();
        STEP(1, 1, 0, xpA_G, xpA_F, xpA_I, xpA_O,
             { xpB_F = MF(xn0, Bx[1], biasC[1]); });
        __syncthreads();
        STEP(2, 0, 1, xpA_G, xpA_F, xpA_I, xpA_O,
             { xpB_I = MF(xn0, Bx[0], biasC[0]); });
        __syncthreads();
        STEP(3, 1, 0, xpA_G, xpA_F, xpA_I, xpA_O,
             { xpB_O = MF(xn0, Bx[3], biasC[3]); });
        __syncthreads();
        // group B (t+4..t+7): uses xpB, builds xpA from xn1 = x(t+8)
        STEP(0, 0, 1, xpB_G, xpB_F, xpB_I, xpB_O,
             { xn0 = ldsx(tB); xpA_G = MF(xn1, Bx[2], biasC[2]); });
        __syncthreads();
        STEP(1, 1, 0, xpB_G, xpB_F, xpB_I, xpB_O,
             { xpA_F = MF(xn1, Bx[1], biasC[1]); });
        __syncthreads();
        STEP(2, 0, 1, xpB_G, xpB_F, xpB_I, xpB_O,
             { xpA_I = MF(xn1, Bx[0], biasC[0]); });
        __syncthreads();
        STEP(3, 1, 0, xpB_G, xpB_F, xpB_I, xpB_O,
             { xpA_O = MF(xn1, Bx[3], biasC[3]); });
        __syncthreads();
    }
#undef STEP

    // h(T) in zbuf[0] (last step writes buf 0). FC head: one (row,ticker)/thread.
    if (tid < RPB * NTK) {
        const int rr = tid >> 3;
        const int tk = tid & 7;
        float a = b_fc[tk];
        const float* wf = w_fc + tk * HD;
        #pragma unroll
        for (int j = 0; j < HD; ++j)
            a = fmaf((float)zbuf[0][rr][j], wf[j], a);
        out[(r0 + rr) * NTK + tk] = a;
    }
}

extern "C" void kernel_launch(void* const* d_in, const int* in_sizes, int n_in,
                              void* d_out, int out_size, void* d_ws, size_t ws_size,
                              hipStream_t stream) {
    const float* x    = (const float*)d_in[0];
    const float* w_ih = (const float*)d_in[1];
    const float* w_hh = (const float*)d_in[2];
    const float* b_ih = (const float*)d_in[3];
    const float* b_hh = (const float*)d_in[4];
    const float* w_fc = (const float*)d_in[5];
    const float* b_fc = (const float*)d_in[6];
    float* out = (float*)d_out;

    const int nx = in_sizes[0];              // B*T*I
    const int B  = nx / (TT * ID);           // 512

    // opt-in to >64KB dynamic LDS (host-side, capture-safe)
    (void)hipFuncSetAttribute((const void*)lstm10,
                              hipFuncAttributeMaxDynamicSharedMemorySize, SHBYTES);

    lstm10<<<dim3(B / RPB), dim3(256), SHBYTES, stream>>>(x, w_ih, w_hh, b_ih, b_hh,
                                                          w_fc, b_fc, out);
}